// Round 6
// baseline (91.372 us; speedup 1.0000x reference)
//
#include <hip/hip_runtime.h>

#define ROWS 8192
#define KDIM 4096
#define NDIM 4096
#define KSEG 4
#define SEGK 1024

typedef float f32x4 __attribute__((ext_vector_type(4)));

// ws layout (floats):
//   w01T : [16][4096]     at 0        (65536)   -- r2-major (TRANSPOSED)
//   w23  : [16][4096]     at 65536    (65536)
//   tpart: [4][8192][16]  at 131072   (524288)

__device__ inline f32x4 fma4(float s, f32x4 w, f32x4 a) {
    a.x = fmaf(s, w.x, a.x);
    a.y = fmaf(s, w.y, a.y);
    a.z = fmaf(s, w.z, a.z);
    a.w = fmaf(s, w.w, a.w);
    return a;
}
__device__ inline f32x4 shfl_xor4(f32x4 v, int m) {
    v.x = __shfl_xor(v.x, m, 64);
    v.y = __shfl_xor(v.y, m, 64);
    v.z = __shfl_xor(v.z, m, 64);
    v.w = __shfl_xor(v.w, m, 64);
    return v;
}
__device__ inline float dot4acc(f32x4 xv, f32x4 wv, float acc) {
    return fmaf(xv.w, wv.w, fmaf(xv.z, wv.z,
           fmaf(xv.y, wv.y, fmaf(xv.x, wv.x, acc))));
}

// ---------------------------------------------------------------------------
// Build W01^T (16x4096, r2-major) and W23 (16x4096) from the TT cores.
// Middle bond r2 has rank 16 -> W = W01 @ W23.
// ---------------------------------------------------------------------------
__global__ __launch_bounds__(256) void tt_prep(
    const float* __restrict__ c0, const float* __restrict__ c1,
    const float* __restrict__ c2, const float* __restrict__ c3,
    float* __restrict__ w01T, float* __restrict__ w23)
{
    int gid = blockIdx.x * 256 + threadIdx.x;  // 0..131071
    if (gid < 65536) {
        // w01T[r2][p], p = n0*64+n1
        int r2 = gid >> 12, p = gid & 4095;
        int n0 = p >> 6, n1 = p & 63;
        float s = 0.f;
        #pragma unroll
        for (int r1 = 0; r1 < 16; ++r1)
            s = fmaf(c0[n0 * 16 + r1], c1[(r1 * 64 + n1) * 16 + r2], s);
        w01T[gid] = s;
    } else {
        // w23[r2][j], j = n2*64+n3
        int g = gid - 65536;
        int r2 = g >> 12, j = g & 4095;
        int n2 = j >> 6, n3 = j & 63;
        float s = 0.f;
        #pragma unroll
        for (int r3 = 0; r3 < 16; ++r3)
            s = fmaf(c2[(r2 * 64 + n2) * 16 + r3], c3[r3 * 64 + n3], s);
        w23[g] = s;
    }
}

// ---------------------------------------------------------------------------
// T = x @ W01 -> tpart[seg][row][16].  Dot form, fully coalesced:
// lane owns k = it*256 + lane*4; every x-load AND w-load is a contiguous
// 1 KB/wave instruction (w01T is r2-major). 8 rows/wave, acc[8][16] scalars.
// 6-stage reduce-scatter butterfly sums k across lanes (static indices only).
// Grid (256 rowblocks, 4 ksegs); 4 waves/block, 8 rows/wave.
// ---------------------------------------------------------------------------
__global__ __launch_bounds__(256) void tt_xw01(
    const float* __restrict__ x, const float* __restrict__ w01T,
    float* __restrict__ tpart)
{
    const int t = threadIdx.x;
    const int lane = t & 63;
    const int wv = t >> 6;            // wave 0..3
    const int row0 = blockIdx.x * 32 + wv * 8;
    const int seg = blockIdx.y;
    const int k0 = seg * SEGK;

    const float* xb = x + (size_t)row0 * KDIM + k0;
    const float* wb = w01T + k0;      // row stride KDIM

    f32x4 A[32];                      // A[r*4+c][e] = acc[row r][r2 = 4c+e]
    #pragma unroll
    for (int i = 0; i < 32; ++i) A[i] = (f32x4)(0.f);

    #pragma unroll
    for (int it = 0; it < SEGK / 256; ++it) {   // 4 iters
        const int kk = it * 256 + lane * 4;
        f32x4 xv[8];
        #pragma unroll
        for (int r = 0; r < 8; ++r)
            xv[r] = __builtin_nontemporal_load(
                (const f32x4*)&xb[(size_t)r * KDIM + kk]);
        #pragma unroll
        for (int r2 = 0; r2 < 16; ++r2) {
            f32x4 wvv = *(const f32x4*)&wb[(size_t)r2 * KDIM + kk];
            #pragma unroll
            for (int r = 0; r < 8; ++r) {
                float v = A[r * 4 + (r2 >> 2)][r2 & 3];
                v = dot4acc(xv[r], wvv, v);
                A[r * 4 + (r2 >> 2)][r2 & 3] = v;
            }
        }
    }

    // Reduce-scatter butterfly over all 64 lanes (bits 5..1 scatter, bit 0
    // plain). Kept flat-index at the end = lane>>1. Static indices only.
    const bool b5 = lane & 32, b4 = lane & 16, b3 = lane & 8,
               b2 = lane & 4,  b1 = lane & 2;
    f32x4 r16[16];
    #pragma unroll
    for (int j = 0; j < 16; ++j) {
        f32x4 send = b5 ? A[j] : A[16 + j];
        f32x4 keep = b5 ? A[16 + j] : A[j];
        r16[j] = keep + shfl_xor4(send, 32);
    }
    f32x4 r8[8];
    #pragma unroll
    for (int j = 0; j < 8; ++j) {
        f32x4 send = b4 ? r16[j] : r16[8 + j];
        f32x4 keep = b4 ? r16[8 + j] : r16[j];
        r8[j] = keep + shfl_xor4(send, 16);
    }
    f32x4 r4[4];
    #pragma unroll
    for (int j = 0; j < 4; ++j) {
        f32x4 send = b3 ? r8[j] : r8[4 + j];
        f32x4 keep = b3 ? r8[4 + j] : r8[j];
        r4[j] = keep + shfl_xor4(send, 8);
    }
    f32x4 r2v[2];
    #pragma unroll
    for (int j = 0; j < 2; ++j) {
        f32x4 send = b2 ? r4[j] : r4[2 + j];
        f32x4 keep = b2 ? r4[2 + j] : r4[j];
        r2v[j] = keep + shfl_xor4(send, 4);
    }
    f32x4 r1;
    {
        f32x4 send = b1 ? r2v[0] : r2v[1];
        f32x4 keep = b1 ? r2v[1] : r2v[0];
        r1 = keep + shfl_xor4(send, 2);
    }
    r1 += shfl_xor4(r1, 1);           // final plain stage (lane pairs equal)

    // Lane (even) holds flat f32x4 #(lane>>1): row = lane>>3, quad = (lane>>1)&3.
    if (!(lane & 1)) {
        int row = lane >> 3;
        int c = (lane >> 1) & 3;
        float* tp = tpart + ((size_t)seg * ROWS + row0 + row) * 16 + c * 4;
        *(f32x4*)tp = r1;
    }
}

// ---------------------------------------------------------------------------
// out = T @ W23. Block: 16 rows x 1024 cols; grid (512, 4) = 2048 blocks.
// Thread owns ONE j-quad: w[16] in regs (64 VGPR), row loop unroll 4.
// Nontemporal out stores (134 MB stream).
// ---------------------------------------------------------------------------
__global__ __launch_bounds__(256) void tt_tw23(
    const float* __restrict__ tpart, const float* __restrict__ w23,
    float* __restrict__ out)
{
    __shared__ float ts[16][16];
    int rb = blockIdx.x;   // row block of 16
    int jb = blockIdx.y;   // col block of 1024
    int t = threadIdx.x;
    int i0 = rb * 16;
    {
        int row = t >> 4, r = t & 15;
        float s = 0.f;
        #pragma unroll
        for (int seg = 0; seg < KSEG; ++seg)
            s += tpart[((size_t)seg * ROWS + i0 + row) * 16 + r];
        ts[row][r] = s;
    }
    __syncthreads();

    int j0 = jb * 1024 + t * 4;
    f32x4 w[16];
    #pragma unroll
    for (int r = 0; r < 16; ++r)
        w[r] = *(const f32x4*)&w23[r * 4096 + j0];

    #pragma unroll 4
    for (int row = 0; row < 16; ++row) {
        const f32x4* trp = (const f32x4*)&ts[row][0];
        f32x4 t0 = trp[0], t1 = trp[1], t2 = trp[2], t3 = trp[3];
        f32x4 a = (f32x4)(0.f);
        a = fma4(t0.x, w[0],  a); a = fma4(t0.y, w[1],  a);
        a = fma4(t0.z, w[2],  a); a = fma4(t0.w, w[3],  a);
        a = fma4(t1.x, w[4],  a); a = fma4(t1.y, w[5],  a);
        a = fma4(t1.z, w[6],  a); a = fma4(t1.w, w[7],  a);
        a = fma4(t2.x, w[8],  a); a = fma4(t2.y, w[9],  a);
        a = fma4(t2.z, w[10], a); a = fma4(t2.w, w[11], a);
        a = fma4(t3.x, w[12], a); a = fma4(t3.y, w[13], a);
        a = fma4(t3.z, w[14], a); a = fma4(t3.w, w[15], a);
        __builtin_nontemporal_store(a, (f32x4*)&out[(size_t)(i0 + row) * 4096 + j0]);
    }
}

extern "C" void kernel_launch(void* const* d_in, const int* in_sizes, int n_in,
                              void* d_out, int out_size, void* d_ws, size_t ws_size,
                              hipStream_t stream) {
    const float* x  = (const float*)d_in[0];
    const float* c0 = (const float*)d_in[1];
    const float* c1 = (const float*)d_in[2];
    const float* c2 = (const float*)d_in[3];
    const float* c3 = (const float*)d_in[4];
    float* out = (float*)d_out;

    float* w01T  = (float*)d_ws;        // 65536 floats
    float* w23   = w01T + 65536;        // 65536 floats
    float* tpart = w23 + 65536;         // 4*131072 floats (2 MB)

    tt_prep<<<512, 256, 0, stream>>>(c0, c1, c2, c3, w01T, w23);
    tt_xw01<<<dim3(256, KSEG), 256, 0, stream>>>(x, w01T, tpart);
    tt_tw23<<<dim3(512, 4), 256, 0, stream>>>(tpart, w23, out);
}

// Round 8
// 84.635 us; speedup vs baseline: 1.0796x; 1.0796x over previous
//
#include <hip/hip_runtime.h>

#define ROWS 8192
#define KDIM 4096
#define NDIM 4096

typedef float f32x4 __attribute__((ext_vector_type(4)));

// ws layout (floats):
//   w01  : [4096][16]        at 0        (65536)   -- k-major, r2 contiguous
//   w23  : [16][4096]        at 65536    (65536)
//   tpart: [nseg][8192][16]  at 131072   (nseg*131072)

__device__ inline f32x4 fma4(float s, f32x4 w, f32x4 a) {
    a.x = fmaf(s, w.x, a.x);
    a.y = fmaf(s, w.y, a.y);
    a.z = fmaf(s, w.z, a.z);
    a.w = fmaf(s, w.w, a.w);
    return a;
}
__device__ inline f32x4 shfl_xor4(f32x4 v, int m) {
    v.x = __shfl_xor(v.x, m, 64);
    v.y = __shfl_xor(v.y, m, 64);
    v.z = __shfl_xor(v.z, m, 64);
    v.w = __shfl_xor(v.w, m, 64);
    return v;
}

// ---------------------------------------------------------------------------
// Build W01 (4096x16, k-major) and W23 (16x4096) from the TT cores.
// Middle bond r2 has rank 16 -> W = W01 @ W23.
// ---------------------------------------------------------------------------
__global__ __launch_bounds__(256) void tt_prep(
    const float* __restrict__ c0, const float* __restrict__ c1,
    const float* __restrict__ c2, const float* __restrict__ c3,
    float* __restrict__ w01, float* __restrict__ w23)
{
    int gid = blockIdx.x * 256 + threadIdx.x;  // 0..131071
    if (gid < 65536) {
        // w01[k][r2], k = n0*64+n1
        int p = gid >> 4, r2 = gid & 15;
        int n0 = p >> 6, n1 = p & 63;
        float s = 0.f;
        #pragma unroll
        for (int r1 = 0; r1 < 16; ++r1)
            s = fmaf(c0[n0 * 16 + r1], c1[(r1 * 64 + n1) * 16 + r2], s);
        w01[gid] = s;
    } else {
        // w23[r2][j], j = n2*64+n3
        int g = gid - 65536;
        int r2 = g >> 12, j = g & 4095;
        int n2 = j >> 6, n3 = j & 63;
        float s = 0.f;
        #pragma unroll
        for (int r3 = 0; r3 < 16; ++r3)
            s = fmaf(c2[(r2 * 64 + n2) * 16 + r3], c3[r3 * 64 + n3], s);
        w23[g] = s;
    }
}

// ---------------------------------------------------------------------------
// T = x @ W01 -> tpart[seg][row][16].  EXACT R5 (verified) inner structure:
// lane: q = lane&3 (r2 quad), klane = lane>>2 (16 k positions, 64 k/iter).
// Per iter: 4 w-loads (coalesced 1 KB/wave) + 8 x-loads : 32 fma4.
// Reduce-scatter butterfly over lane bits 5,4,3 (scatter) + 2 (plain);
// static indices only (rule #20). 8 rows/wave, acc[8] f32x4.
// Grid (256 rowblocks, NSEG ksegs); 4 waves/block.
// ---------------------------------------------------------------------------
template <int SEGK>
__global__ __launch_bounds__(256) void tt_xw01(
    const float* __restrict__ x, const float* __restrict__ w01,
    float* __restrict__ tpart)
{
    const int t = threadIdx.x;
    const int lane = t & 63;
    const int wv = t >> 6;            // wave 0..3
    const int q = lane & 3;           // r2 quad
    const int klane = lane >> 2;      // 0..15
    const int row0 = blockIdx.x * 32 + wv * 8;
    const int seg = blockIdx.y;
    const int k0 = seg * SEGK;

    const float* xb = x + (size_t)row0 * KDIM + k0;
    const float* wb = w01 + (size_t)k0 * 16;

    f32x4 acc[8];
    #pragma unroll
    for (int r = 0; r < 8; ++r) acc[r] = (f32x4)(0.f);

    #pragma unroll 2
    for (int it = 0; it < SEGK / 64; ++it) {
        const int kk0 = it * 64 + klane * 4;   // lane's first k of 4
        f32x4 wq[4];
        #pragma unroll
        for (int kk = 0; kk < 4; ++kk)
            wq[kk] = *(const f32x4*)&wb[(size_t)(kk0 + kk) * 16 + q * 4];
        f32x4 xv[8];
        #pragma unroll
        for (int r = 0; r < 8; ++r)
            xv[r] = __builtin_nontemporal_load(
                (const f32x4*)&xb[(size_t)r * KDIM + kk0]);
        #pragma unroll
        for (int kk = 0; kk < 4; ++kk)
            #pragma unroll
            for (int r = 0; r < 8; ++r)
                acc[r] = fma4(xv[r][kk], wq[kk], acc[r]);
    }

    // Reduce over 16 klanes (lane bits 2..5): scatter bits 5,4,3; plain bit 2.
    const bool b5 = lane & 32, b4 = lane & 16, b3 = lane & 8;
    f32x4 s1[4];
    #pragma unroll
    for (int j = 0; j < 4; ++j) {
        f32x4 send = b5 ? acc[j] : acc[4 + j];
        f32x4 keep = b5 ? acc[4 + j] : acc[j];
        s1[j] = keep + shfl_xor4(send, 32);
    }
    f32x4 s2[2];
    #pragma unroll
    for (int j = 0; j < 2; ++j) {
        f32x4 send = b4 ? s1[j] : s1[2 + j];
        f32x4 keep = b4 ? s1[2 + j] : s1[j];
        s2[j] = keep + shfl_xor4(send, 16);
    }
    f32x4 s3;
    {
        f32x4 send = b3 ? s2[0] : s2[1];
        f32x4 keep = b3 ? s2[1] : s2[0];
        s3 = keep + shfl_xor4(send, 8);
    }
    s3 += shfl_xor4(s3, 4);           // plain stage: lane-bit2 pairs identical

    // Lane holds row = (lane>>3)&7 for quad q; writers: bit2 == 0.
    if ((lane & 4) == 0) {
        int row = (lane >> 3) & 7;
        float* tp = tpart + ((size_t)seg * ROWS + row0 + row) * 16 + q * 4;
        *(f32x4*)tp = s3;
    }
}

// ---------------------------------------------------------------------------
// out = T @ W23. Block: 32 rows x 1024 cols; grid (256, 4) = 1024 blocks.
// Thread owns ONE j-quad: w[16] in regs, reused across 32 rows. NT stores.
// ---------------------------------------------------------------------------
__global__ __launch_bounds__(256) void tt_tw23(
    const float* __restrict__ tpart, const float* __restrict__ w23,
    float* __restrict__ out, int nseg)
{
    __shared__ float ts[32][16];
    int rb = blockIdx.x;   // row block of 32
    int jb = blockIdx.y;   // col block of 1024
    int t = threadIdx.x;
    int i0 = rb * 32;
    {
        int row = t >> 4, r = t & 15;
        float s0 = 0.f, s1 = 0.f;
        for (int seg = 0; seg < nseg; ++seg) {
            s0 += tpart[((size_t)seg * ROWS + i0 + row) * 16 + r];
            s1 += tpart[((size_t)seg * ROWS + i0 + 16 + row) * 16 + r];
        }
        ts[row][r] = s0;
        ts[row + 16][r] = s1;
    }
    __syncthreads();

    int j0 = jb * 1024 + t * 4;
    f32x4 w[16];
    #pragma unroll
    for (int r = 0; r < 16; ++r)
        w[r] = *(const f32x4*)&w23[r * 4096 + j0];

    #pragma unroll 2
    for (int row = 0; row < 32; ++row) {
        const f32x4* trp = (const f32x4*)&ts[row][0];
        f32x4 t0 = trp[0], t1 = trp[1], t2 = trp[2], t3 = trp[3];
        f32x4 a = (f32x4)(0.f);
        a = fma4(t0.x, w[0],  a); a = fma4(t0.y, w[1],  a);
        a = fma4(t0.z, w[2],  a); a = fma4(t0.w, w[3],  a);
        a = fma4(t1.x, w[4],  a); a = fma4(t1.y, w[5],  a);
        a = fma4(t1.z, w[6],  a); a = fma4(t1.w, w[7],  a);
        a = fma4(t2.x, w[8],  a); a = fma4(t2.y, w[9],  a);
        a = fma4(t2.z, w[10], a); a = fma4(t2.w, w[11], a);
        a = fma4(t3.x, w[12], a); a = fma4(t3.y, w[13], a);
        a = fma4(t3.z, w[14], a); a = fma4(t3.w, w[15], a);
        __builtin_nontemporal_store(a, (f32x4*)&out[(size_t)(i0 + row) * 4096 + j0]);
    }
}

extern "C" void kernel_launch(void* const* d_in, const int* in_sizes, int n_in,
                              void* d_out, int out_size, void* d_ws, size_t ws_size,
                              hipStream_t stream) {
    const float* x  = (const float*)d_in[0];
    const float* c0 = (const float*)d_in[1];
    const float* c1 = (const float*)d_in[2];
    const float* c2 = (const float*)d_in[3];
    const float* c3 = (const float*)d_in[4];
    float* out = (float*)d_out;

    float* w01   = (float*)d_ws;        // 65536 floats
    float* w23   = w01 + 65536;         // 65536 floats
    float* tpart = w23 + 65536;         // nseg*131072 floats

    // K-split: 8 segments (4.7 MB ws) if it fits, else 4 (2.6 MB).
    const int nseg = (ws_size >= (size_t)(131072 + 8 * 131072) * 4) ? 8 : 4;

    tt_prep<<<512, 256, 0, stream>>>(c0, c1, c2, c3, w01, w23);
    if (nseg == 8)
        tt_xw01<512><<<dim3(256, 8), 256, 0, stream>>>(x, w01, tpart);
    else
        tt_xw01<1024><<<dim3(256, 4), 256, 0, stream>>>(x, w01, tpart);
    tt_tw23<<<dim3(256, 4), 256, 0, stream>>>(tpart, w23, out, nseg);
}